// Round 13
// baseline (317.918 us; speedup 1.0000x reference)
//
#include <hip/hip_runtime.h>
#include <stdint.h>
#include <math.h>

// Algebra (validated R3-R7): only the cls token queries.
//   q = x0 @ Wq + bq ; r[h][d] = sum_c q[h*64+c] * Wk[d][h*64+c]
//   logits[h][n] = (r[h] . x[n])/8 ; p = softmax ; y_h = sum_n p_h[n] x[n]
//   ctx_h = y_h @ Wv_h + bv ; out = ctx @ Wo + bo
// R21: per-kernel data (R20): attn=78.8us (VALU 24%, 1.78TB/s, no spills),
// aux kernels ~40us, harness fixed ~145us. attn limited by per-wave MLP in
// pass 1 (unroll-4 at the 64-VGPR heuristic cap). This round:
//   - pass 1: explicit 8-row load batches (16 float4 in flight/wave, ~2x MLP);
//     launch_bounds(1024,4) cap=128 VGPR gives room. Reduce code verbatim.
//   - r fused into attn head (R13-proven P1, Wk from L2) -> r_kernel + WkT
//     transpose + 4MB r round-trip eliminated. 4 launches (was 5).

// ---------------- gemm k-split body (proven R8) ----------------
__device__ __forceinline__ void gemm_ks_body(
    const float* __restrict__ A, long a_row_stride, int a_col_off_mult,
    const float* __restrict__ W, const float* __restrict__ bias,
    float* __restrict__ C, int rt, int jt, int t,
    float (*a_s)[512], float (*red_s)[4][64]) {
  const int w = t >> 6, lane = t & 63;

#pragma unroll
  for (int l = 0; l < 2; ++l) {
    int flat4 = t + l * 256;
    int arow = flat4 >> 7;
    int k4 = (flat4 & 127) * 4;
    float4 v = *(const float4*)&A[(long)(rt * 4 + arow) * a_row_stride +
                                  (long)jt * a_col_off_mult + k4];
    a_s[arow][k4] = v.x; a_s[arow][k4 + 1] = v.y;
    a_s[arow][k4 + 2] = v.z; a_s[arow][k4 + 3] = v.w;
  }
  __syncthreads();

  const int j = jt * 64 + lane;
  float acc0 = 0.f, acc1 = 0.f, acc2 = 0.f, acc3 = 0.f;
  const float* wp = W + (long)(w * 128) * 512 + j;
  const float* ap = &a_s[0][w * 128];
#pragma unroll 8
  for (int k = 0; k < 128; ++k) {
    float wv = wp[(long)k * 512];
    acc0 += ap[k] * wv;
    acc1 += ap[512 + k] * wv;
    acc2 += ap[1024 + k] * wv;
    acc3 += ap[1536 + k] * wv;
  }
  if (w > 0) {
    red_s[w - 1][0][lane] = acc0;
    red_s[w - 1][1][lane] = acc1;
    red_s[w - 1][2][lane] = acc2;
    red_s[w - 1][3][lane] = acc3;
  }
  __syncthreads();
  if (w == 0) {
#pragma unroll
    for (int rr = 0; rr < 3; ++rr) {
      acc0 += red_s[rr][0][lane];
      acc1 += red_s[rr][1][lane];
      acc2 += red_s[rr][2][lane];
      acc3 += red_s[rr][3][lane];
    }
    const float b = bias[j];
    C[(long)(rt * 4 + 0) * 512 + j] = acc0 + b;
    C[(long)(rt * 4 + 1) * 512 + j] = acc1 + b;
    C[(long)(rt * 4 + 2) * 512 + j] = acc2 + b;
    C[(long)(rt * 4 + 3) * 512 + j] = acc3 + b;
  }
}

__global__ __launch_bounds__(256) void gemm_ks_kernel(
    const float* __restrict__ A, long a_row_stride, int a_col_off_mult,
    const float* __restrict__ W, const float* __restrict__ bias,
    float* __restrict__ C) {
  __shared__ float a_s[4][512];
  __shared__ float red_s[3][4][64];
  gemm_ks_body(A, a_row_stride, a_col_off_mult, W, bias, C,
               blockIdx.x, blockIdx.y, threadIdx.x, a_s, red_s);
}

// ---------------- per-row logit reduce (R13-proven, verbatim) ----------------
__device__ __forceinline__ void row_reduce(
    const float4 xa, const float4 xb4, const float rv[4][8],
    int lane, int hg, float (*p_s)[256], int n) {
  float acc[4];
#pragma unroll
  for (int hi = 0; hi < 4; ++hi)
    acc[hi] = xa.x * rv[hi][0] + xa.y * rv[hi][1] + xa.z * rv[hi][2] + xa.w * rv[hi][3]
            + xb4.x * rv[hi][4] + xb4.y * rv[hi][5] + xb4.z * rv[hi][6] + xb4.w * rv[hi][7];
#pragma unroll
  for (int j = 0; j < 2; ++j) {
    float v = (lane & 2) ? acc[j] : acc[j + 2];
    float tt = __shfl_xor(v, 2);
    acc[j] = ((lane & 2) ? acc[j + 2] : acc[j]) + tt;
  }
  {
    float v = (lane & 1) ? acc[0] : acc[1];
    float tt = __shfl_xor(v, 1);
    acc[0] = ((lane & 1) ? acc[1] : acc[0]) + tt;
  }
  acc[0] += __shfl_xor(acc[0], 4);
  acc[0] += __shfl_xor(acc[0], 8);
  acc[0] += __shfl_xor(acc[0], 16);
  acc[0] += __shfl_xor(acc[0], 32);
  if (lane < 4) p_s[hg * 4 + lane][n] = acc[0] * 0.125f;
}

// ---------------- attn: r + logits + softmax + y, one block per bs ----------
__global__ __launch_bounds__(1024, 4) void attn_kernel(
    const float* __restrict__ x, const float* __restrict__ q_all,
    const float* __restrict__ Wk, float* __restrict__ Y) {
  const int bs = blockIdx.x;
  const int t = threadIdx.x;
  const int w = t >> 6, lane = t & 63;
  const float* xb = x + (long)bs * 131072;
  __shared__ float r_s[4096];     // 16 KB
  __shared__ float p_s[8][256];   // 8 KB: logits -> probabilities
  __shared__ float yp[8][512];    // 16 KB: pass-2 partials

  const int hg = w & 1;     // head group: heads hg*4 .. hg*4+3
  const int rw = w >> 1;    // row group: rows rw*32 .. rw*32+31

  // ---- r-phase (R13 P1 pattern): thread t -> d = t>>1, heads (t&1)*4..+3 ----
  {
    const int d = t >> 1, hh = t & 1;
    const float* wrow = Wk + (long)d * 512 + hh * 256;
    const float* qp = q_all + (long)bs * 512 + hh * 256;
#pragma unroll
    for (int hi = 0; hi < 4; ++hi) {
      float racc = 0.f;
#pragma unroll
      for (int c4 = 0; c4 < 16; ++c4) {
        float4 wv = *(const float4*)&wrow[hi * 64 + c4 * 4];
        float4 qv = *(const float4*)&qp[hi * 64 + c4 * 4];
        racc += qv.x * wv.x + qv.y * wv.y + qv.z * wv.z + qv.w * wv.w;
      }
      r_s[(hh * 4 + hi) * 512 + d] = racc;
    }
  }
  __syncthreads();

  // ---- rv: our 4 heads' r fragments (32 regs) ----
  float rv[4][8];
#pragma unroll
  for (int hi = 0; hi < 4; ++hi) {
    const int h = hg * 4 + hi;
    float4 a = *(const float4*)&r_s[h * 512 + lane * 8];
    float4 b = *(const float4*)&r_s[h * 512 + lane * 8 + 4];
    rv[hi][0] = a.x; rv[hi][1] = a.y; rv[hi][2] = a.z; rv[hi][3] = a.w;
    rv[hi][4] = b.x; rv[hi][5] = b.y; rv[hi][6] = b.z; rv[hi][7] = b.w;
  }

  // ---- pass 1: logits, 4 batches of 8 rows (16 float4 loads in flight) ----
#pragma unroll
  for (int ib = 0; ib < 4; ++ib) {
    const int n0 = rw * 32 + ib * 8;
    const float* xr = xb + (long)n0 * 512 + lane * 8;
    float4 a0 = *(const float4*)(xr +    0), b0 = *(const float4*)(xr +    4);
    float4 a1 = *(const float4*)(xr +  512), b1 = *(const float4*)(xr +  516);
    float4 a2 = *(const float4*)(xr + 1024), b2 = *(const float4*)(xr + 1028);
    float4 a3 = *(const float4*)(xr + 1536), b3 = *(const float4*)(xr + 1540);
    float4 a4 = *(const float4*)(xr + 2048), b4 = *(const float4*)(xr + 2052);
    float4 a5 = *(const float4*)(xr + 2560), b5 = *(const float4*)(xr + 2564);
    float4 a6 = *(const float4*)(xr + 3072), b6 = *(const float4*)(xr + 3076);
    float4 a7 = *(const float4*)(xr + 3584), b7 = *(const float4*)(xr + 3588);
    row_reduce(a0, b0, rv, lane, hg, p_s, n0 + 0);
    row_reduce(a1, b1, rv, lane, hg, p_s, n0 + 1);
    row_reduce(a2, b2, rv, lane, hg, p_s, n0 + 2);
    row_reduce(a3, b3, rv, lane, hg, p_s, n0 + 3);
    row_reduce(a4, b4, rv, lane, hg, p_s, n0 + 4);
    row_reduce(a5, b5, rv, lane, hg, p_s, n0 + 5);
    row_reduce(a6, b6, rv, lane, hg, p_s, n0 + 6);
    row_reduce(a7, b7, rv, lane, hg, p_s, n0 + 7);
  }
  __syncthreads();

  // ---- softmax: wave w < 8 handles head w (proven) ----
  if (w < 8) {
    float4 lv = *(const float4*)&p_s[w][lane * 4];
    float m = fmaxf(fmaxf(lv.x, lv.y), fmaxf(lv.z, lv.w));
    for (int o = 32; o; o >>= 1) m = fmaxf(m, __shfl_xor(m, o));
    float e0 = __expf(lv.x - m), e1 = __expf(lv.y - m);
    float e2 = __expf(lv.z - m), e3 = __expf(lv.w - m);
    float s = e0 + e1 + e2 + e3;
    for (int o = 32; o; o >>= 1) s += __shfl_xor(s, o);
    const float inv = 1.f / s;
    *(float4*)&p_s[w][lane * 4] = make_float4(e0 * inv, e1 * inv, e2 * inv, e3 * inv);
  }
  __syncthreads();

  // ---- pass 2: y_h[d] = sum_n p[h][n] x[n][d], n split in halves ----
  const int d = t & 511;
  const int half = t >> 9;
  float acc[8] = {};
  const float* xb2 = xb + ((long)half * 128) * 512 + d;
#pragma unroll 8
  for (int n = 0; n < 128; ++n) {
    float xv = xb2[(long)n * 512];
#pragma unroll
    for (int h = 0; h < 8; ++h)
      acc[h] += p_s[h][half * 128 + n] * xv;
  }
  if (half == 1) {
#pragma unroll
    for (int h = 0; h < 8; ++h) yp[h][d] = acc[h];
  }
  __syncthreads();
  if (half == 0) {
#pragma unroll
    for (int h = 0; h < 8; ++h)
      Y[(long)bs * 4096 + h * 512 + d] = acc[h] + yp[h][d];
  }
}

extern "C" void kernel_launch(void* const* d_in, const int* in_sizes, int n_in,
                              void* d_out, int out_size, void* d_ws, size_t ws_size,
                              hipStream_t stream) {
  (void)in_sizes; (void)n_in; (void)out_size; (void)ws_size;
  const float* x  = (const float*)d_in[0];
  const float* Wq = (const float*)d_in[1];
  const float* bq = (const float*)d_in[2];
  const float* Wk = (const float*)d_in[3];
  const float* bk = (const float*)d_in[4];  (void)bk;  // softmax-invariant
  const float* Wv = (const float*)d_in[5];
  const float* bv = (const float*)d_in[6];
  const float* Wo = (const float*)d_in[7];
  const float* bo = (const float*)d_in[8];
  float* out = (float*)d_out;

  float* q_ws = (float*)d_ws;      // 256*512  = 0.5 MiB
  float* Y    = q_ws + 131072;     // 256*4096 = 4 MiB
  float* ctx  = Y + 1048576;       // 256*512  = 0.5 MiB

  gemm_ks_kernel<<<dim3(64, 8), 256, 0, stream>>>(x, 131072L, 0, Wq, bq, q_ws);
  attn_kernel<<<256, 1024, 0, stream>>>(x, q_ws, Wk, Y);
  gemm_ks_kernel<<<dim3(64, 8), 256, 0, stream>>>(Y, 4096L, 512, Wv, bv, ctx);
  gemm_ks_kernel<<<dim3(64, 8), 256, 0, stream>>>(ctx, 512L, 0, Wo, bo, out);
}